// Round 9
// baseline (236.124 us; speedup 1.0000x reference)
//
#include <hip/hip_runtime.h>
#include <hip/hip_bf16.h>
#include <math.h>

#define C 384
#define NF 16
#define H 256
#define Bb 4
#define Kk 2048
#define Nn 16384
#define MB 32           // nodes per block (2 m-tiles)
#define LDA 392         // act row stride in shorts

typedef __attribute__((ext_vector_type(8))) short bf16x8;
typedef __attribute__((ext_vector_type(4))) float f32x4;
typedef __attribute__((ext_vector_type(4))) short s16x4;

// ws layout (shorts), fragment-linear: [ntile][kchunk][ln(16)][kq(32)]
#define POS_OFF 0            // pos_w  F=384 K=32
#define Q1_OFF  12288        // q_w1*q_ln_g   F=384 K=384
#define Q2_OFF  159744       // q_w2          F=384 K=384
#define M1_OFF  307200       // m_w1*m_ln_g   F=256 K=384
#define M2_OFF  405504       // m_w2          F=256 K=256
#define M3_OFF  471040       // m_w3 padded [16][256]
#define W_TOTAL 475136
#define NCONV   ((W_TOTAL + 255) / 256)   // 1856 conv blocks
// float constants after the shorts
#define GQ_OFF 0
#define CQ_OFF 384
#define GM_OFF 768
#define CM_OFF 1024

__device__ __attribute__((always_inline)) inline short f2bf(float x) {
    return __builtin_bit_cast(short, __float2bfloat16(x));
}
__device__ __attribute__((always_inline)) inline float bf2f(short s) {
    return __bfloat162float(__builtin_bit_cast(__hip_bfloat16, s));
}
__device__ __attribute__((always_inline)) inline float silu(float v) {
    return v * __builtin_amdgcn_rcpf(1.f + __expf(-v));
}
__device__ __attribute__((always_inline)) inline s16x4 pack4(f32x4 v) {
    __hip_bfloat162 p0 = __float22bfloat162_rn(float2{v[0], v[1]});
    __hip_bfloat162 p1 = __float22bfloat162_rn(float2{v[2], v[3]});
    s16x4 o;
    o[0] = __builtin_bit_cast(short, p0.x);
    o[1] = __builtin_bit_cast(short, p0.y);
    o[2] = __builtin_bit_cast(short, p1.x);
    o[3] = __builtin_bit_cast(short, p1.y);
    return o;
}

// ---- prep: weight f32->bf16 fragment swizzle (blocks < NCONV) + LN-const fold ----
__global__ __launch_bounds__(256) void prep(
    const float* __restrict__ pos_w, const float* __restrict__ q_w1,
    const float* __restrict__ q_w2,  const float* __restrict__ m_w1,
    const float* __restrict__ m_w2,  const float* __restrict__ m_w3,
    const float* __restrict__ q_ln_g, const float* __restrict__ q_ln_b,
    const float* __restrict__ m_ln_g, const float* __restrict__ m_ln_b,
    const float* __restrict__ q_b1,   const float* __restrict__ m_b1,
    short* __restrict__ ws, float* __restrict__ cst)
{
    __shared__ float rg[4], rc[4];
    int tid = threadIdx.x;
    int blk = blockIdx.x;
    if (blk < NCONV) {
        int i = blk * 256 + tid;
        if (i >= W_TOTAL) return;
        const float* src; int off, K;
        if      (i < Q1_OFF) { src = pos_w; off = POS_OFF; K = 32; }
        else if (i < Q2_OFF) { src = q_w1;  off = Q1_OFF;  K = 384; }
        else if (i < M1_OFF) { src = q_w2;  off = Q2_OFF;  K = 384; }
        else if (i < M2_OFF) { src = m_w1;  off = M1_OFF;  K = 384; }
        else if (i < M3_OFF) { src = m_w2;  off = M2_OFF;  K = 256; }
        else                 { src = m_w3;  off = M3_OFF;  K = 256; }
        int t = i - off;
        int chunk = t >> 9, r = t & 511;
        int ln = r >> 5, kq = r & 31;
        int NKm = K >> 5;
        int ntg = chunk / NKm, kk = chunk - ntg * NKm;
        int f = ntg * 16 + ln, k = kk * 32 + kq;
        float v;
        if (off == M3_OFF) v = (f < 3) ? m_w3[f * 256 + k] : 0.f;
        else               v = src[(size_t)f * K + k];
        if (off == Q1_OFF) v *= q_ln_g[k];
        if (off == M1_OFF) v *= m_ln_g[k];
        ws[i] = f2bf(v);
        return;
    }
    // fold blocks: one feature per block
    int f = blk - NCONV;   // 0..639
    const float *Wsrc, *lng, *lnb, *bias; int fr, go, co;
    if (f < 384) { Wsrc = q_w1; lng = q_ln_g; lnb = q_ln_b; bias = q_b1; fr = f;      go = GQ_OFF; co = CQ_OFF; }
    else         { Wsrc = m_w1; lng = m_ln_g; lnb = m_ln_b; bias = m_b1; fr = f - 384; go = GM_OFF; co = CM_OFF; }
    float g = 0.f, c = 0.f;
    for (int k = tid; k < 384; k += 256) {
        float wv = Wsrc[(size_t)fr * 384 + k];
        g += bf2f(f2bf(wv * lng[k]));   // match MFMA's bf16-rounded weights
        c += wv * lnb[k];
    }
    #pragma unroll
    for (int d = 1; d < 64; d <<= 1) { g += __shfl_xor(g, d); c += __shfl_xor(c, d); }
    if ((tid & 63) == 0) { rg[tid >> 6] = g; rc[tid >> 6] = c; }
    __syncthreads();
    if (tid == 0) {
        cst[go + fr] = rg[0] + rg[1] + rg[2] + rg[3];
        cst[co + fr] = rc[0] + rc[1] + rc[2] + rc[3] + bias[fr];
    }
}

// In-place FC layer, 2-deep pipelined k-loop, transposed D (weights as A-op):
// thread (q,ln) holds D[f=FB+nt*16+q*4+r][m=mt*16+ln], mt in {0,1}.
template<int K, int NT, int NTN, int KN, bool SILU_, bool MASK, bool LNIN, bool STATS>
__device__ __attribute__((always_inline)) inline void layer_ip(
    const short* __restrict__ W, const float* __restrict__ cb,
    const float* __restrict__ Gf, int FB,
    const short* __restrict__ Wn, int FBn,
    bf16x8 (&bin)[6],
    short (*__restrict__ xs)[LDA],
    float (*__restrict__ sc1)[4], float (*__restrict__ sc2)[4],
    const float* __restrict__ wmask, int w, int q, int ln)
{
    constexpr int NK = K / 32;
    const short* bp[NT];
    #pragma unroll
    for (int nt = 0; nt < NT; ++nt)
        bp[nt] = W + ((size_t)(FB / 16 + nt) * NK) * 512 + ln * 32 + q * 8;

    f32x4 acc[2][NT];
    #pragma unroll
    for (int mt = 0; mt < 2; ++mt)
        #pragma unroll
        for (int nt = 0; nt < NT; ++nt)
            acc[mt][nt] = (f32x4){0.f, 0.f, 0.f, 0.f};

    bf16x8 b0[NT], b1[NT], a0[2], a1[2];
    #pragma unroll
    for (int nt = 0; nt < NT; ++nt) b0[nt] = bin[nt];
    #pragma unroll
    for (int mt = 0; mt < 2; ++mt) a0[mt] = *(const bf16x8*)&xs[mt * 16 + ln][q * 8];

    #pragma unroll
    for (int kc = 0; kc < NK; kc += 2) {
        #pragma unroll
        for (int nt = 0; nt < NT; ++nt) b1[nt] = *(const bf16x8*)(bp[nt] + (kc + 1) * 512);
        #pragma unroll
        for (int mt = 0; mt < 2; ++mt) a1[mt] = *(const bf16x8*)&xs[mt * 16 + ln][(kc + 1) * 32 + q * 8];
        #pragma unroll
        for (int nt = 0; nt < NT; ++nt)
            #pragma unroll
            for (int mt = 0; mt < 2; ++mt)
                acc[mt][nt] = __builtin_amdgcn_mfma_f32_16x16x32_bf16(b0[nt], a0[mt], acc[mt][nt], 0, 0, 0);
        if (kc + 2 < NK) {
            #pragma unroll
            for (int nt = 0; nt < NT; ++nt) b0[nt] = *(const bf16x8*)(bp[nt] + (kc + 2) * 512);
            #pragma unroll
            for (int mt = 0; mt < 2; ++mt) a0[mt] = *(const bf16x8*)&xs[mt * 16 + ln][(kc + 2) * 32 + q * 8];
        }
        #pragma unroll
        for (int nt = 0; nt < NT; ++nt)
            #pragma unroll
            for (int mt = 0; mt < 2; ++mt)
                acc[mt][nt] = __builtin_amdgcn_mfma_f32_16x16x32_bf16(b1[nt], a1[mt], acc[mt][nt], 0, 0, 0);
    }

    // prefetch NEXT layer's first k-chunk — rides across barrier + epilogue
    #pragma unroll
    for (int nt = 0; nt < NTN; ++nt)
        bin[nt] = *(const bf16x8*)(Wn + ((size_t)(FBn / 16 + nt) * (KN / 32)) * 512 + ln * 32 + q * 8);

    __syncthreads();   // all reads of xs complete before any in-place write

    float mk[2], rstd[2], rm[2];
    #pragma unroll
    for (int mt = 0; mt < 2; ++mt) {
        int m = mt * 16 + ln;
        if (MASK) mk[mt] = wmask[m];
        if (LNIN) {
            f32x4 p1 = *(const f32x4*)&sc1[m][0];
            f32x4 p2 = *(const f32x4*)&sc2[m][0];
            float t1 = p1[0] + p1[1] + p1[2] + p1[3];
            float t2 = p2[0] + p2[1] + p2[2] + p2[3];
            float mean = t1 * (1.f / 384.f);
            float var  = t2 * (1.f / 384.f) - mean * mean;
            rstd[mt] = rsqrtf(var + 1e-5f);
            rm[mt]   = rstd[mt] * mean;
        }
    }

    float s1[2] = {0.f, 0.f}, s2[2] = {0.f, 0.f};
    #pragma unroll
    for (int nt = 0; nt < NT; ++nt) {
        const int f0 = FB + nt * 16 + q * 4;
        f32x4 c4 = *(const f32x4*)&cb[f0];
        f32x4 g4;
        if (LNIN) g4 = *(const f32x4*)&Gf[f0];
        #pragma unroll
        for (int mt = 0; mt < 2; ++mt) {
            f32x4 vv;
            #pragma unroll
            for (int r = 0; r < 4; ++r) {
                float v;
                if (LNIN) v = fmaf(rstd[mt], acc[mt][nt][r], fmaf(-rm[mt], g4[r], c4[r]));
                else      v = acc[mt][nt][r] + c4[r];
                if (SILU_) v = silu(v);
                if (MASK) v *= mk[mt];
                if (STATS) { s1[mt] += v; s2[mt] += v * v; }
                vv[r] = v;
            }
            *(s16x4*)&xs[mt * 16 + ln][f0] = pack4(vv);
        }
    }
    if (STATS) {
        #pragma unroll
        for (int mt = 0; mt < 2; ++mt) {
            s1[mt] += __shfl_xor(s1[mt], 16); s2[mt] += __shfl_xor(s2[mt], 16);
            s1[mt] += __shfl_xor(s1[mt], 32); s2[mt] += __shfl_xor(s2[mt], 32);
        }
        if (q == 0) {
            #pragma unroll
            for (int mt = 0; mt < 2; ++mt) {
                sc1[mt * 16 + ln][w] = s1[mt];
                sc2[mt * 16 + ln][w] = s2[mt];
            }
        }
    }
    __syncthreads();   // writes (xs and sc) visible before next layer
}

__global__ __launch_bounds__(256, 3) void upxi32(
    const float* __restrict__ s_parent, const float* __restrict__ mu_k,
    const float* __restrict__ R_k,      const float* __restrict__ s_k,
    const int*   __restrict__ a_idx,    const float* __restrict__ node_mask,
    const float* __restrict__ pos01,
    const float* __restrict__ pos_b,
    const float* __restrict__ q_b2,     const float* __restrict__ m_b2,
    const float* __restrict__ m_b3,
    const short* __restrict__ wsb,      const float* __restrict__ cst,
    float* __restrict__ out)
{
    __shared__ short xs[MB][LDA];
    __shared__ float sc1[MB][4];
    __shared__ float sc2[MB][4];
    __shared__ float wmask[MB], wpos[MB];
    __shared__ int   widx[MB];

    const int tid  = threadIdx.x;
    const int w    = tid >> 6;
    const int lane = tid & 63;
    const int q    = lane >> 4;
    const int ln   = lane & 15;

    const int g0 = blockIdx.x * MB;
    const int b  = g0 / Nn;
    const int n0 = g0 % Nn;

    // prefetch Q1 first k-chunk immediately (hidden under scalars+sincos+pos)
    bf16x8 bin[6];
    #pragma unroll
    for (int nt = 0; nt < 6; ++nt)
        bin[nt] = *(const bf16x8*)(wsb + Q1_OFF + ((size_t)(w * 6 + nt) * 12) * 512 + ln * 32 + q * 8);

    if (tid < MB) {
        int gi = b * Nn + n0 + tid;
        int idx = a_idx[gi];
        widx[tid]  = min(max(idx, 0), Kk - 1);
        wmask[tid] = node_mask[gi];
        wpos[tid]  = pos01[gi];
    }
    __syncthreads();

    const float* gbase = s_parent + (long)b * Kk * C;

    // ---- pos layer (transposed D): pos_w as A-operand, feats as B-operand ----
    {
        const short* pos_wb = wsb + POS_OFF;
        const bool use_sin = (q < 2);
        const int kb = (q & 1) * 8;
        bf16x8 a[2];
        #pragma unroll
        for (int mt = 0; mt < 2; ++mt) {
            float p = wpos[mt * 16 + ln];
            #pragma unroll
            for (int e = 0; e < 8; ++e) {
                float fr = (float)(1 << (kb + e)) * 3.14159265358979323846f;
                float sv, cv;
                __sincosf(p * fr, &sv, &cv);
                a[mt][e] = f2bf(use_sin ? sv : cv);
            }
        }
        f32x4 acc[2][6];
        #pragma unroll
        for (int mt = 0; mt < 2; ++mt)
            #pragma unroll
            for (int nt = 0; nt < 6; ++nt)
                acc[mt][nt] = (f32x4){0.f, 0.f, 0.f, 0.f};
        #pragma unroll
        for (int nt = 0; nt < 6; ++nt) {
            bf16x8 bfr = *(const bf16x8*)&pos_wb[(w * 6 + nt) * 512 + ln * 32 + q * 8];
            #pragma unroll
            for (int mt = 0; mt < 2; ++mt)
                acc[mt][nt] = __builtin_amdgcn_mfma_f32_16x16x32_bf16(bfr, a[mt], acc[mt][nt], 0, 0, 0);
        }
        float mk[2]; int ix[2];
        #pragma unroll
        for (int mt = 0; mt < 2; ++mt) {
            mk[mt] = wmask[mt * 16 + ln];
            ix[mt] = widx[mt * 16 + ln];
        }
        float s1[2] = {0.f, 0.f}, s2[2] = {0.f, 0.f};
        #pragma unroll
        for (int nt = 0; nt < 6; ++nt) {
            const int f0 = w * 96 + nt * 16 + q * 4;
            f32x4 pb4 = *(const f32x4*)&pos_b[f0];
            #pragma unroll
            for (int mt = 0; mt < 2; ++mt) {
                f32x4 g4 = *(const f32x4*)&gbase[(long)ix[mt] * C + f0];
                f32x4 vv;
                #pragma unroll
                for (int r = 0; r < 4; ++r) {
                    float v = (acc[mt][nt][r] + pb4[r]) * mk[mt] + g4[r];
                    s1[mt] += v; s2[mt] += v * v;
                    vv[r] = v;
                }
                *(s16x4*)&xs[mt * 16 + ln][f0] = pack4(vv);
            }
        }
        #pragma unroll
        for (int mt = 0; mt < 2; ++mt) {
            s1[mt] += __shfl_xor(s1[mt], 16); s2[mt] += __shfl_xor(s2[mt], 16);
            s1[mt] += __shfl_xor(s1[mt], 32); s2[mt] += __shfl_xor(s2[mt], 32);
        }
        if (q == 0) {
            #pragma unroll
            for (int mt = 0; mt < 2; ++mt) {
                sc1[mt * 16 + ln][w] = s1[mt];
                sc2[mt * 16 + ln][w] = s2[mt];
            }
        }
    }
    __syncthreads();

    // Q1: LN(q) folded: v = silu(rstd*acc - rm*Gq + Cq)
    layer_ip<384, 6, 6, 384, true,  false, true,  false>(wsb + Q1_OFF, cst + CQ_OFF,
        cst + GQ_OFF, w * 96, wsb + Q2_OFF, w * 96, bin, xs, sc1, sc2, wmask, w, q, ln);
    // Q2: (acc + b2)*mask, stats for m-LN
    layer_ip<384, 6, 4, 384, false, true,  false, true >(wsb + Q2_OFF, q_b2,
        nullptr, w * 96, wsb + M1_OFF, w * 64, bin, xs, sc1, sc2, wmask, w, q, ln);
    // M1: LN(m) folded: v = silu(rstd*acc - rm*Gm + Cm)
    layer_ip<384, 4, 4, 256, true,  false, true,  false>(wsb + M1_OFF, cst + CM_OFF,
        cst + GM_OFF, w * 64, wsb + M2_OFF, w * 64, bin, xs, sc1, sc2, wmask, w, q, ln);
    // M2: silu(acc + b2)
    layer_ip<256, 4, 1, 256, true,  false, false, false>(wsb + M2_OFF, m_b2,
        nullptr, w * 64, wsb + M3_OFF, 0, bin, xs, sc1, sc2, wmask, w, q, ln);

    // ---- tail: 256->3 MFMA transposed (waves 0,1 own m-tiles 0,1), tanh*1.5 ----
    if (w < 2) {
        const short* W3 = wsb + M3_OFF;
        f32x4 a3 = (f32x4){0.f, 0.f, 0.f, 0.f};
        #pragma unroll
        for (int kc = 0; kc < 8; ++kc) {
            bf16x8 a  = *(const bf16x8*)&xs[w * 16 + ln][kc * 32 + q * 8];
            bf16x8 bf = *(const bf16x8*)(W3 + kc * 512 + ln * 32 + q * 8);
            a3 = __builtin_amdgcn_mfma_f32_16x16x32_bf16(bf, a, a3, 0, 0, 0);
        }
        if (q == 0) {
            int m = w * 16 + ln;
            float mkv = wmask[m];
            #pragma unroll
            for (int r = 0; r < 3; ++r) {
                float v = (a3[r] + m_b3[r]) * mkv;
                sc1[m][r] = tanhf(v) * 1.5f;
            }
        }
        // ---- rigid apply + outputs (same-wave lanes; in-wave order suffices) ----
        if (lane < 16) {
            int m = w * 16 + lane;
            long gi = (long)b * Nn + n0 + m;
            long pk = (long)b * Kk + widx[m];
            float mkv = wmask[m];
            float xv[3], yv[3], xiv[3];
            #pragma unroll
            for (int j = 0; j < 3; ++j) {
                xiv[j] = sc1[m][j];
                float sc = fmaxf(s_k[pk * 3 + j], 1e-8f);
                xv[j] = xiv[j] * sc;
            }
            #pragma unroll
            for (int i = 0; i < 3; ++i) {
                float a = R_k[pk * 9 + i * 3 + 0] * xv[0]
                        + R_k[pk * 9 + i * 3 + 1] * xv[1]
                        + R_k[pk * 9 + i * 3 + 2] * xv[2]
                        + mu_k[pk * 3 + i];
                yv[i] = a * mkv * 10.f;
            }
            float* o0 = out;
            float* o1 = out + (long)Bb * Nn * 3;
            float* o2 = out + (long)Bb * Nn * 6;
            #pragma unroll
            for (int j = 0; j < 3; ++j) { o0[gi * 3 + j] = xiv[j]; o1[gi * 3 + j] = yv[j]; }
            o2[gi] = wpos[m];
        }
    }
}

extern "C" void kernel_launch(void* const* d_in, const int* in_sizes, int n_in,
                              void* d_out, int out_size, void* d_ws, size_t ws_size,
                              hipStream_t stream) {
    const float* s_parent = (const float*)d_in[0];
    const float* mu_k     = (const float*)d_in[1];
    const float* R_k      = (const float*)d_in[2];
    const float* s_k      = (const float*)d_in[3];
    const int*   a_idx    = (const int*)  d_in[4];
    const float* node_mask= (const float*)d_in[5];
    const float* pos01    = (const float*)d_in[6];
    const float* pos_w    = (const float*)d_in[7];
    const float* pos_b    = (const float*)d_in[8];
    const float* q_ln_g   = (const float*)d_in[9];
    const float* q_ln_b   = (const float*)d_in[10];
    const float* q_w1     = (const float*)d_in[11];
    const float* q_b1     = (const float*)d_in[12];
    const float* q_w2     = (const float*)d_in[13];
    const float* q_b2     = (const float*)d_in[14];
    const float* m_ln_g   = (const float*)d_in[15];
    const float* m_ln_b   = (const float*)d_in[16];
    const float* m_w1     = (const float*)d_in[17];
    const float* m_b1     = (const float*)d_in[18];
    const float* m_w2     = (const float*)d_in[19];
    const float* m_b2     = (const float*)d_in[20];
    const float* m_w3     = (const float*)d_in[21];
    const float* m_b3     = (const float*)d_in[22];

    short* wsb = (short*)d_ws;
    float* cst = (float*)(wsb + W_TOTAL);

    prep<<<NCONV + 640, 256, 0, stream>>>(
        pos_w, q_w1, q_w2, m_w1, m_w2, m_w3,
        q_ln_g, q_ln_b, m_ln_g, m_ln_b, q_b1, m_b1, wsb, cst);

    int blocks = (Bb * Nn) / MB;  // 2048
    upxi32<<<blocks, 256, 0, stream>>>(
        s_parent, mu_k, R_k, s_k, a_idx, node_mask, pos01,
        pos_b, q_b2, m_b2, m_b3, wsb, cst, (float*)d_out);
}

// Round 10
// 197.318 us; speedup vs baseline: 1.1967x; 1.1967x over previous
//
#include <hip/hip_runtime.h>
#include <hip/hip_bf16.h>
#include <math.h>

#define C 384
#define NF 16
#define H 256
#define Bb 4
#define Kk 2048
#define Nn 16384
#define MB 64           // nodes per block (4 m-tiles)
#define LDA 392         // act row stride in shorts

typedef __attribute__((ext_vector_type(8))) short bf16x8;
typedef __attribute__((ext_vector_type(4))) float f32x4;
typedef __attribute__((ext_vector_type(4))) short s16x4;

// ws layout (shorts), fragment-linear: [ntile][kchunk][ln(16)][kq(32)]
#define POS_OFF 0            // pos_w  F=384 K=32
#define Q1_OFF  12288        // q_w1*q_ln_g   F=384 K=384
#define Q2_OFF  159744       // q_w2          F=384 K=384
#define M1_OFF  307200       // m_w1*m_ln_g   F=256 K=384
#define M2_OFF  405504       // m_w2          F=256 K=256
#define M3_OFF  471040       // m_w3 padded [16][256]
#define W_TOTAL 475136
#define NCONV   ((W_TOTAL + 255) / 256)
// float constants after the shorts
#define GQ_OFF 0
#define CQ_OFF 384
#define GM_OFF 768
#define CM_OFF 1024

// barrier that does NOT drain vmcnt — weight prefetches stay in flight.
// LDS ordering only needs lgkmcnt(0); "memory" clobber stops compiler motion.
#define BAR() __asm__ volatile("s_waitcnt lgkmcnt(0)\ns_barrier" ::: "memory")

__device__ __attribute__((always_inline)) inline short f2bf(float x) {
    return __builtin_bit_cast(short, __float2bfloat16(x));
}
__device__ __attribute__((always_inline)) inline float bf2f(short s) {
    return __bfloat162float(__builtin_bit_cast(__hip_bfloat16, s));
}
__device__ __attribute__((always_inline)) inline float silu(float v) {
    return v * __builtin_amdgcn_rcpf(1.f + __expf(-v));
}
__device__ __attribute__((always_inline)) inline s16x4 pack4(f32x4 v) {
    __hip_bfloat162 p0 = __float22bfloat162_rn(float2{v[0], v[1]});
    __hip_bfloat162 p1 = __float22bfloat162_rn(float2{v[2], v[3]});
    s16x4 o;
    o[0] = __builtin_bit_cast(short, p0.x);
    o[1] = __builtin_bit_cast(short, p0.y);
    o[2] = __builtin_bit_cast(short, p1.x);
    o[3] = __builtin_bit_cast(short, p1.y);
    return o;
}

// ---- prep: weight f32->bf16 fragment swizzle (blocks < NCONV) + LN-const fold ----
__global__ __launch_bounds__(256) void prep(
    const float* __restrict__ pos_w, const float* __restrict__ q_w1,
    const float* __restrict__ q_w2,  const float* __restrict__ m_w1,
    const float* __restrict__ m_w2,  const float* __restrict__ m_w3,
    const float* __restrict__ q_ln_g, const float* __restrict__ q_ln_b,
    const float* __restrict__ m_ln_g, const float* __restrict__ m_ln_b,
    const float* __restrict__ q_b1,   const float* __restrict__ m_b1,
    short* __restrict__ ws, float* __restrict__ cst)
{
    __shared__ float rg[4], rc[4];
    int tid = threadIdx.x;
    int blk = blockIdx.x;
    if (blk < NCONV) {
        int i = blk * 256 + tid;
        if (i >= W_TOTAL) return;
        const float* src; int off, K;
        if      (i < Q1_OFF) { src = pos_w; off = POS_OFF; K = 32; }
        else if (i < Q2_OFF) { src = q_w1;  off = Q1_OFF;  K = 384; }
        else if (i < M1_OFF) { src = q_w2;  off = Q2_OFF;  K = 384; }
        else if (i < M2_OFF) { src = m_w1;  off = M1_OFF;  K = 384; }
        else if (i < M3_OFF) { src = m_w2;  off = M2_OFF;  K = 256; }
        else                 { src = m_w3;  off = M3_OFF;  K = 256; }
        int t = i - off;
        int chunk = t >> 9, r = t & 511;
        int ln = r >> 5, kq = r & 31;
        int NKm = K >> 5;
        int ntg = chunk / NKm, kk = chunk - ntg * NKm;
        int f = ntg * 16 + ln, k = kk * 32 + kq;
        float v;
        if (off == M3_OFF) v = (f < 3) ? m_w3[f * 256 + k] : 0.f;
        else               v = src[(size_t)f * K + k];
        if (off == Q1_OFF) v *= q_ln_g[k];
        if (off == M1_OFF) v *= m_ln_g[k];
        ws[i] = f2bf(v);
        return;
    }
    int f = blk - NCONV;   // 0..639
    const float *Wsrc, *lng, *lnb, *bias; int fr, go, co;
    if (f < 384) { Wsrc = q_w1; lng = q_ln_g; lnb = q_ln_b; bias = q_b1; fr = f;      go = GQ_OFF; co = CQ_OFF; }
    else         { Wsrc = m_w1; lng = m_ln_g; lnb = m_ln_b; bias = m_b1; fr = f - 384; go = GM_OFF; co = CM_OFF; }
    float g = 0.f, c = 0.f;
    for (int k = tid; k < 384; k += 256) {
        float wv = Wsrc[(size_t)fr * 384 + k];
        g += bf2f(f2bf(wv * lng[k]));   // match MFMA's bf16-rounded weights
        c += wv * lnb[k];
    }
    #pragma unroll
    for (int d = 1; d < 64; d <<= 1) { g += __shfl_xor(g, d); c += __shfl_xor(c, d); }
    if ((tid & 63) == 0) { rg[tid >> 6] = g; rc[tid >> 6] = c; }
    __syncthreads();
    if (tid == 0) {
        cst[go + fr] = rg[0] + rg[1] + rg[2] + rg[3];
        cst[co + fr] = rc[0] + rc[1] + rc[2] + rc[3] + bias[fr];
    }
}

// In-place FC layer, distance-2 rotating B prefetch (3 chunk buffers),
// transposed D (weights as A-op): thread (q,ln) holds D[f][m=mt*16+ln].
template<int K, int NT, int NTN, int KN, bool SILU_, bool MASK, bool LNIN, bool STATS>
__device__ __attribute__((always_inline)) inline void layer_ip(
    const short* __restrict__ W, const float* __restrict__ cb,
    const float* __restrict__ Gf, int FB,
    const short* __restrict__ Wn, int FBn,
    bf16x8 (&bin)[6],
    short (*__restrict__ xs)[LDA],
    float (*__restrict__ sc1)[4], float (*__restrict__ sc2)[4],
    const float* __restrict__ wmask, int w, int q, int ln)
{
    constexpr int NK = K / 32;
    const short* bp = W + (size_t)(FB / 16) * NK * 512 + ln * 32 + q * 8;

    f32x4 acc[4][NT];
    #pragma unroll
    for (int mt = 0; mt < 4; ++mt)
        #pragma unroll
        for (int nt = 0; nt < NT; ++nt)
            acc[mt][nt] = (f32x4){0.f, 0.f, 0.f, 0.f};

    bf16x8 Bbuf[3][NT], Abuf[2][4];
    #pragma unroll
    for (int nt = 0; nt < NT; ++nt) Bbuf[0][nt] = bin[nt];                   // chunk 0 (prefetched last layer)
    #pragma unroll
    for (int nt = 0; nt < NT; ++nt)
        Bbuf[1][nt] = *(const bf16x8*)(bp + (size_t)nt * NK * 512 + 512);    // chunk 1
    #pragma unroll
    for (int mt = 0; mt < 4; ++mt)
        Abuf[0][mt] = *(const bf16x8*)&xs[mt * 16 + ln][q * 8];              // chunk 0

    #pragma unroll
    for (int kc = 0; kc < NK; ++kc) {
        if (kc + 2 < NK) {
            #pragma unroll
            for (int nt = 0; nt < NT; ++nt)
                Bbuf[(kc + 2) % 3][nt] =
                    *(const bf16x8*)(bp + (size_t)nt * NK * 512 + (kc + 2) * 512);
        } else if (kc + 2 == NK) {
            // cross-layer prefetch takes the distance-2 slot
            #pragma unroll
            for (int nt = 0; nt < NTN; ++nt)
                bin[nt] = *(const bf16x8*)(Wn + ((size_t)(FBn / 16 + nt) * (KN / 32)) * 512 + ln * 32 + q * 8);
        }
        if (kc + 1 < NK) {
            #pragma unroll
            for (int mt = 0; mt < 4; ++mt)
                Abuf[(kc + 1) & 1][mt] =
                    *(const bf16x8*)&xs[mt * 16 + ln][(kc + 1) * 32 + q * 8];
        }
        #pragma unroll
        for (int nt = 0; nt < NT; ++nt)
            #pragma unroll
            for (int mt = 0; mt < 4; ++mt)
                acc[mt][nt] = __builtin_amdgcn_mfma_f32_16x16x32_bf16(
                    Bbuf[kc % 3][nt], Abuf[kc & 1][mt], acc[mt][nt], 0, 0, 0);
    }

    BAR();   // all reads of xs complete before any in-place write (lgkm only)

    float mk[4], rstd[4], rm[4];
    #pragma unroll
    for (int mt = 0; mt < 4; ++mt) {
        int m = mt * 16 + ln;
        if (MASK) mk[mt] = wmask[m];
        if (LNIN) {
            f32x4 p1 = *(const f32x4*)&sc1[m][0];
            f32x4 p2 = *(const f32x4*)&sc2[m][0];
            float t1 = p1[0] + p1[1] + p1[2] + p1[3];
            float t2 = p2[0] + p2[1] + p2[2] + p2[3];
            float mean = t1 * (1.f / 384.f);
            float var  = t2 * (1.f / 384.f) - mean * mean;
            rstd[mt] = rsqrtf(var + 1e-5f);
            rm[mt]   = rstd[mt] * mean;
        }
    }

    float s1[4] = {0.f,0.f,0.f,0.f}, s2[4] = {0.f,0.f,0.f,0.f};
    #pragma unroll
    for (int nt = 0; nt < NT; ++nt) {
        const int f0 = FB + nt * 16 + q * 4;
        f32x4 c4 = *(const f32x4*)&cb[f0];
        f32x4 g4;
        if (LNIN) g4 = *(const f32x4*)&Gf[f0];
        #pragma unroll
        for (int mt = 0; mt < 4; ++mt) {
            f32x4 vv;
            #pragma unroll
            for (int r = 0; r < 4; ++r) {
                float v;
                if (LNIN) v = fmaf(rstd[mt], acc[mt][nt][r], fmaf(-rm[mt], g4[r], c4[r]));
                else      v = acc[mt][nt][r] + c4[r];
                if (SILU_) v = silu(v);
                if (MASK) v *= mk[mt];
                if (STATS) { s1[mt] += v; s2[mt] += v * v; }
                vv[r] = v;
            }
            *(s16x4*)&xs[mt * 16 + ln][f0] = pack4(vv);
        }
    }
    if (STATS) {
        #pragma unroll
        for (int mt = 0; mt < 4; ++mt) {
            s1[mt] += __shfl_xor(s1[mt], 16); s2[mt] += __shfl_xor(s2[mt], 16);
            s1[mt] += __shfl_xor(s1[mt], 32); s2[mt] += __shfl_xor(s2[mt], 32);
        }
        if (q == 0) {
            #pragma unroll
            for (int mt = 0; mt < 4; ++mt) {
                sc1[mt * 16 + ln][w] = s1[mt];
                sc2[mt * 16 + ln][w] = s2[mt];
            }
        }
    }
    BAR();   // writes (xs and sc) visible before next layer
}

__global__ __launch_bounds__(256, 2) void upxi64(
    const float* __restrict__ s_parent, const float* __restrict__ mu_k,
    const float* __restrict__ R_k,      const float* __restrict__ s_k,
    const int*   __restrict__ a_idx,    const float* __restrict__ node_mask,
    const float* __restrict__ pos01,
    const float* __restrict__ pos_b,
    const float* __restrict__ q_b2,     const float* __restrict__ m_b2,
    const float* __restrict__ m_b3,
    const short* __restrict__ wsb,      const float* __restrict__ cst,
    float* __restrict__ out)
{
    __shared__ short xs[MB][LDA];
    __shared__ float sc1[MB][4];
    __shared__ float sc2[MB][4];
    __shared__ float wmask[MB], wpos[MB];
    __shared__ int   widx[MB];

    const int tid  = threadIdx.x;
    const int w    = tid >> 6;
    const int lane = tid & 63;
    const int q    = lane >> 4;
    const int ln   = lane & 15;

    const int g0 = blockIdx.x * MB;
    const int b  = g0 / Nn;
    const int n0 = g0 % Nn;

    // prefetch Q1 first k-chunk immediately (hidden under scalars+sincos+pos)
    bf16x8 bin[6];
    #pragma unroll
    for (int nt = 0; nt < 6; ++nt)
        bin[nt] = *(const bf16x8*)(wsb + Q1_OFF + ((size_t)(w * 6 + nt) * 12) * 512 + ln * 32 + q * 8);

    if (tid < MB) {
        int gi = b * Nn + n0 + tid;
        int idx = a_idx[gi];
        widx[tid]  = min(max(idx, 0), Kk - 1);
        wmask[tid] = node_mask[gi];
        wpos[tid]  = pos01[gi];
    }
    BAR();

    const float* gbase = s_parent + (long)b * Kk * C;

    // ---- pos layer (transposed D): pos_w as A-operand, feats as B-operand ----
    {
        const short* pos_wb = wsb + POS_OFF;
        const bool use_sin = (q < 2);
        const int kb = (q & 1) * 8;
        bf16x8 a[4];
        #pragma unroll
        for (int mt = 0; mt < 4; ++mt) {
            float p = wpos[mt * 16 + ln];
            #pragma unroll
            for (int e = 0; e < 8; ++e) {
                float fr = (float)(1 << (kb + e)) * 3.14159265358979323846f;
                float sv, cv;
                __sincosf(p * fr, &sv, &cv);
                a[mt][e] = f2bf(use_sin ? sv : cv);
            }
        }
        f32x4 acc[4][6];
        #pragma unroll
        for (int mt = 0; mt < 4; ++mt)
            #pragma unroll
            for (int nt = 0; nt < 6; ++nt)
                acc[mt][nt] = (f32x4){0.f, 0.f, 0.f, 0.f};
        #pragma unroll
        for (int nt = 0; nt < 6; ++nt) {
            bf16x8 bfr = *(const bf16x8*)&pos_wb[(w * 6 + nt) * 512 + ln * 32 + q * 8];
            #pragma unroll
            for (int mt = 0; mt < 4; ++mt)
                acc[mt][nt] = __builtin_amdgcn_mfma_f32_16x16x32_bf16(bfr, a[mt], acc[mt][nt], 0, 0, 0);
        }
        float mk[4]; int ix[4];
        #pragma unroll
        for (int mt = 0; mt < 4; ++mt) {
            mk[mt] = wmask[mt * 16 + ln];
            ix[mt] = widx[mt * 16 + ln];
        }
        float s1[4] = {0.f,0.f,0.f,0.f}, s2[4] = {0.f,0.f,0.f,0.f};
        #pragma unroll
        for (int nt = 0; nt < 6; ++nt) {
            const int f0 = w * 96 + nt * 16 + q * 4;
            f32x4 pb4 = *(const f32x4*)&pos_b[f0];
            #pragma unroll
            for (int mt = 0; mt < 4; ++mt) {
                f32x4 g4 = *(const f32x4*)&gbase[(long)ix[mt] * C + f0];
                f32x4 vv;
                #pragma unroll
                for (int r = 0; r < 4; ++r) {
                    float v = (acc[mt][nt][r] + pb4[r]) * mk[mt] + g4[r];
                    s1[mt] += v; s2[mt] += v * v;
                    vv[r] = v;
                }
                *(s16x4*)&xs[mt * 16 + ln][f0] = pack4(vv);
            }
        }
        #pragma unroll
        for (int mt = 0; mt < 4; ++mt) {
            s1[mt] += __shfl_xor(s1[mt], 16); s2[mt] += __shfl_xor(s2[mt], 16);
            s1[mt] += __shfl_xor(s1[mt], 32); s2[mt] += __shfl_xor(s2[mt], 32);
        }
        if (q == 0) {
            #pragma unroll
            for (int mt = 0; mt < 4; ++mt) {
                sc1[mt * 16 + ln][w] = s1[mt];
                sc2[mt * 16 + ln][w] = s2[mt];
            }
        }
    }
    BAR();

    // Q1: LN(q) folded: v = silu(rstd*acc - rm*Gq + Cq)
    layer_ip<384, 6, 6, 384, true,  false, true,  false>(wsb + Q1_OFF, cst + CQ_OFF,
        cst + GQ_OFF, w * 96, wsb + Q2_OFF, w * 96, bin, xs, sc1, sc2, wmask, w, q, ln);
    // Q2: (acc + b2)*mask, stats for m-LN
    layer_ip<384, 6, 4, 384, false, true,  false, true >(wsb + Q2_OFF, q_b2,
        nullptr, w * 96, wsb + M1_OFF, w * 64, bin, xs, sc1, sc2, wmask, w, q, ln);
    // M1: LN(m) folded: v = silu(rstd*acc - rm*Gm + Cm)
    layer_ip<384, 4, 4, 256, true,  false, true,  false>(wsb + M1_OFF, cst + CM_OFF,
        cst + GM_OFF, w * 64, wsb + M2_OFF, w * 64, bin, xs, sc1, sc2, wmask, w, q, ln);
    // M2: silu(acc + b2)
    layer_ip<256, 4, 1, 256, true,  false, false, false>(wsb + M2_OFF, m_b2,
        nullptr, w * 64, wsb + M3_OFF, 0, bin, xs, sc1, sc2, wmask, w, q, ln);

    // ---- tail: 256->3 MFMA transposed (wave w owns m-tile w), tanh*1.5 ----
    {
        const short* W3 = wsb + M3_OFF;
        f32x4 a3 = (f32x4){0.f, 0.f, 0.f, 0.f};
        #pragma unroll
        for (int kc = 0; kc < 8; ++kc) {
            bf16x8 a  = *(const bf16x8*)&xs[w * 16 + ln][kc * 32 + q * 8];
            bf16x8 bf = (kc == 0) ? bin[0]
                      : *(const bf16x8*)(W3 + kc * 512 + ln * 32 + q * 8);
            a3 = __builtin_amdgcn_mfma_f32_16x16x32_bf16(bf, a, a3, 0, 0, 0);
        }
        if (q == 0) {
            int m = w * 16 + ln;
            float mkv = wmask[m];
            #pragma unroll
            for (int r = 0; r < 3; ++r) {
                float v = (a3[r] + m_b3[r]) * mkv;
                sc1[m][r] = tanhf(v) * 1.5f;
            }
        }
    }

    // ---- rigid apply + outputs (same-wave lanes; in-wave order suffices) ----
    if (lane < 16) {
        int m = w * 16 + lane;
        long gi = (long)b * Nn + n0 + m;
        long pk = (long)b * Kk + widx[m];
        float mkv = wmask[m];
        float xv[3], yv[3], xiv[3];
        #pragma unroll
        for (int j = 0; j < 3; ++j) {
            xiv[j] = sc1[m][j];
            float sc = fmaxf(s_k[pk * 3 + j], 1e-8f);
            xv[j] = xiv[j] * sc;
        }
        #pragma unroll
        for (int i = 0; i < 3; ++i) {
            float a = R_k[pk * 9 + i * 3 + 0] * xv[0]
                    + R_k[pk * 9 + i * 3 + 1] * xv[1]
                    + R_k[pk * 9 + i * 3 + 2] * xv[2]
                    + mu_k[pk * 3 + i];
            yv[i] = a * mkv * 10.f;
        }
        float* o0 = out;
        float* o1 = out + (long)Bb * Nn * 3;
        float* o2 = out + (long)Bb * Nn * 6;
        #pragma unroll
        for (int j = 0; j < 3; ++j) { o0[gi * 3 + j] = xiv[j]; o1[gi * 3 + j] = yv[j]; }
        o2[gi] = wpos[m];
    }
}

extern "C" void kernel_launch(void* const* d_in, const int* in_sizes, int n_in,
                              void* d_out, int out_size, void* d_ws, size_t ws_size,
                              hipStream_t stream) {
    const float* s_parent = (const float*)d_in[0];
    const float* mu_k     = (const float*)d_in[1];
    const float* R_k      = (const float*)d_in[2];
    const float* s_k      = (const float*)d_in[3];
    const int*   a_idx    = (const int*)  d_in[4];
    const float* node_mask= (const float*)d_in[5];
    const float* pos01    = (const float*)d_in[6];
    const float* pos_w    = (const float*)d_in[7];
    const float* pos_b    = (const float*)d_in[8];
    const float* q_ln_g   = (const float*)d_in[9];
    const float* q_ln_b   = (const float*)d_in[10];
    const float* q_w1     = (const float*)d_in[11];
    const float* q_b1     = (const float*)d_in[12];
    const float* q_w2     = (const float*)d_in[13];
    const float* q_b2     = (const float*)d_in[14];
    const float* m_ln_g   = (const float*)d_in[15];
    const float* m_ln_b   = (const float*)d_in[16];
    const float* m_w1     = (const float*)d_in[17];
    const float* m_b1     = (const float*)d_in[18];
    const float* m_w2     = (const float*)d_in[19];
    const float* m_b2     = (const float*)d_in[20];
    const float* m_w3     = (const float*)d_in[21];
    const float* m_b3     = (const float*)d_in[22];

    short* wsb = (short*)d_ws;
    float* cst = (float*)(wsb + W_TOTAL);

    prep<<<NCONV + 640, 256, 0, stream>>>(
        pos_w, q_w1, q_w2, m_w1, m_w2, m_w3,
        q_ln_g, q_ln_b, m_ln_g, m_ln_b, q_b1, m_b1, wsb, cst);

    int blocks = (Bb * Nn) / MB;  // 1024
    upxi64<<<blocks, 256, 0, stream>>>(
        s_parent, mu_k, R_k, s_k, a_idx, node_mask, pos01,
        pos_b, q_b2, m_b2, m_b3, wsb, cst, (float*)d_out);
}

// Round 11
// 195.165 us; speedup vs baseline: 1.2099x; 1.0110x over previous
//
#include <hip/hip_runtime.h>
#include <hip/hip_bf16.h>
#include <math.h>

#define C 384
#define NF 16
#define H 256
#define Bb 4
#define Kk 2048
#define Nn 16384
#define MB 64           // nodes per block (4 m-tiles)
#define LDA 392         // act row stride in shorts

typedef __attribute__((ext_vector_type(8))) short bf16x8;
typedef __attribute__((ext_vector_type(4))) float f32x4;
typedef __attribute__((ext_vector_type(4))) short s16x4;

// ws layout (shorts), fragment-linear: [ntile][kchunk][ln(16)][kq(32)]
#define POS_OFF 0            // pos_w  F=384 K=32
#define Q1_OFF  12288        // q_w1*q_ln_g   F=384 K=384
#define Q2_OFF  159744       // q_w2          F=384 K=384
#define M1_OFF  307200       // m_w1*m_ln_g   F=256 K=384
#define M2_OFF  405504       // m_w2          F=256 K=256
#define M3_OFF  471040       // m_w3 padded [16][256]
#define W_TOTAL 475136
#define NCONV   ((W_TOTAL + 255) / 256)
// float constants after the shorts
#define GQ_OFF 0
#define CQ_OFF 384
#define GM_OFF 768
#define CM_OFF 1024

// barrier that does NOT drain vmcnt — weight prefetches stay in flight.
#define BAR() __asm__ volatile("s_waitcnt lgkmcnt(0)\ns_barrier" ::: "memory")

__device__ __attribute__((always_inline)) inline short f2bf(float x) {
    return __builtin_bit_cast(short, __float2bfloat16(x));
}
__device__ __attribute__((always_inline)) inline float bf2f(short s) {
    return __bfloat162float(__builtin_bit_cast(__hip_bfloat16, s));
}
__device__ __attribute__((always_inline)) inline float silu(float v) {
    return v * __builtin_amdgcn_rcpf(1.f + __expf(-v));
}
__device__ __attribute__((always_inline)) inline s16x4 pack4(f32x4 v) {
    __hip_bfloat162 p0 = __float22bfloat162_rn(float2{v[0], v[1]});
    __hip_bfloat162 p1 = __float22bfloat162_rn(float2{v[2], v[3]});
    s16x4 o;
    o[0] = __builtin_bit_cast(short, p0.x);
    o[1] = __builtin_bit_cast(short, p0.y);
    o[2] = __builtin_bit_cast(short, p1.x);
    o[3] = __builtin_bit_cast(short, p1.y);
    return o;
}

// ---- prep: weight f32->bf16 fragment swizzle (blocks < NCONV) + LN-const fold ----
__global__ __launch_bounds__(256) void prep(
    const float* __restrict__ pos_w, const float* __restrict__ q_w1,
    const float* __restrict__ q_w2,  const float* __restrict__ m_w1,
    const float* __restrict__ m_w2,  const float* __restrict__ m_w3,
    const float* __restrict__ q_ln_g, const float* __restrict__ q_ln_b,
    const float* __restrict__ m_ln_g, const float* __restrict__ m_ln_b,
    const float* __restrict__ q_b1,   const float* __restrict__ m_b1,
    short* __restrict__ ws, float* __restrict__ cst)
{
    __shared__ float rg[4], rc[4];
    int tid = threadIdx.x;
    int blk = blockIdx.x;
    if (blk < NCONV) {
        int i = blk * 256 + tid;
        if (i >= W_TOTAL) return;
        const float* src; int off, K;
        if      (i < Q1_OFF) { src = pos_w; off = POS_OFF; K = 32; }
        else if (i < Q2_OFF) { src = q_w1;  off = Q1_OFF;  K = 384; }
        else if (i < M1_OFF) { src = q_w2;  off = Q2_OFF;  K = 384; }
        else if (i < M2_OFF) { src = m_w1;  off = M1_OFF;  K = 384; }
        else if (i < M3_OFF) { src = m_w2;  off = M2_OFF;  K = 256; }
        else                 { src = m_w3;  off = M3_OFF;  K = 256; }
        int t = i - off;
        int chunk = t >> 9, r = t & 511;
        int ln = r >> 5, kq = r & 31;
        int NKm = K >> 5;
        int ntg = chunk / NKm, kk = chunk - ntg * NKm;
        int f = ntg * 16 + ln, k = kk * 32 + kq;
        float v;
        if (off == M3_OFF) v = (f < 3) ? m_w3[f * 256 + k] : 0.f;
        else               v = src[(size_t)f * K + k];
        if (off == Q1_OFF) v *= q_ln_g[k];
        if (off == M1_OFF) v *= m_ln_g[k];
        ws[i] = f2bf(v);
        return;
    }
    int f = blk - NCONV;   // 0..639
    const float *Wsrc, *lng, *lnb, *bias; int fr, go, co;
    if (f < 384) { Wsrc = q_w1; lng = q_ln_g; lnb = q_ln_b; bias = q_b1; fr = f;      go = GQ_OFF; co = CQ_OFF; }
    else         { Wsrc = m_w1; lng = m_ln_g; lnb = m_ln_b; bias = m_b1; fr = f - 384; go = GM_OFF; co = CM_OFF; }
    float g = 0.f, c = 0.f;
    for (int k = tid; k < 384; k += 256) {
        float wv = Wsrc[(size_t)fr * 384 + k];
        g += bf2f(f2bf(wv * lng[k]));   // match MFMA's bf16-rounded weights
        c += wv * lnb[k];
    }
    #pragma unroll
    for (int d = 1; d < 64; d <<= 1) { g += __shfl_xor(g, d); c += __shfl_xor(c, d); }
    if ((tid & 63) == 0) { rg[tid >> 6] = g; rc[tid >> 6] = c; }
    __syncthreads();
    if (tid == 0) {
        cst[go + fr] = rg[0] + rg[1] + rg[2] + rg[3];
        cst[co + fr] = rc[0] + rc[1] + rc[2] + rc[3] + bias[fr];
    }
}

// In-place FC layer: distance-2 rotating B prefetch (3 chunk buffers), A read
// directly from LDS each chunk (compiler schedules ds_read/lgkmcnt), transposed
// D (weights as A-op): thread (q,ln) holds D[f][m=mt*16+ln].
template<int K, int NT, int NTN, int KN, bool SILU_, bool MASK, bool LNIN, bool STATS>
__device__ __attribute__((always_inline)) inline void layer_ip(
    const short* __restrict__ W, const float* __restrict__ cb,
    const float* __restrict__ Gf, int FB,
    const short* __restrict__ Wn, int FBn,
    bf16x8 (&bin)[6],
    short (*__restrict__ xs)[LDA],
    float (*__restrict__ sc1)[4], float (*__restrict__ sc2)[4],
    const float* __restrict__ wmask, int w, int q, int ln)
{
    constexpr int NK = K / 32;
    const short* bp = W + (size_t)(FB / 16) * NK * 512 + ln * 32 + q * 8;

    f32x4 acc[4][NT];
    #pragma unroll
    for (int mt = 0; mt < 4; ++mt)
        #pragma unroll
        for (int nt = 0; nt < NT; ++nt)
            acc[mt][nt] = (f32x4){0.f, 0.f, 0.f, 0.f};

    bf16x8 Bbuf[3][NT];
    #pragma unroll
    for (int nt = 0; nt < NT; ++nt) Bbuf[0][nt] = bin[nt];                   // chunk 0
    #pragma unroll
    for (int nt = 0; nt < NT; ++nt)
        Bbuf[1][nt] = *(const bf16x8*)(bp + (size_t)nt * NK * 512 + 512);    // chunk 1

    #pragma unroll
    for (int kc = 0; kc < NK; ++kc) {
        if (kc + 2 < NK) {
            #pragma unroll
            for (int nt = 0; nt < NT; ++nt)
                Bbuf[(kc + 2) % 3][nt] =
                    *(const bf16x8*)(bp + (size_t)nt * NK * 512 + (kc + 2) * 512);
        } else if (kc + 2 == NK) {
            // cross-layer prefetch takes the distance-2 slot; BAR keeps it alive
            #pragma unroll
            for (int nt = 0; nt < NTN; ++nt)
                bin[nt] = *(const bf16x8*)(Wn + ((size_t)(FBn / 16 + nt) * (KN / 32)) * 512 + ln * 32 + q * 8);
        }
        bf16x8 a[4];
        #pragma unroll
        for (int mt = 0; mt < 4; ++mt)
            a[mt] = *(const bf16x8*)&xs[mt * 16 + ln][kc * 32 + q * 8];
        #pragma unroll
        for (int nt = 0; nt < NT; ++nt)
            #pragma unroll
            for (int mt = 0; mt < 4; ++mt)
                acc[mt][nt] = __builtin_amdgcn_mfma_f32_16x16x32_bf16(
                    Bbuf[kc % 3][nt], a[mt], acc[mt][nt], 0, 0, 0);
    }

    BAR();   // all reads of xs complete before any in-place write (lgkm only)

    float mk[4], rstd[4], rm[4];
    #pragma unroll
    for (int mt = 0; mt < 4; ++mt) {
        int m = mt * 16 + ln;
        if (MASK) mk[mt] = wmask[m];
        if (LNIN) {
            f32x4 p1 = *(const f32x4*)&sc1[m][0];
            f32x4 p2 = *(const f32x4*)&sc2[m][0];
            float t1 = p1[0] + p1[1] + p1[2] + p1[3];
            float t2 = p2[0] + p2[1] + p2[2] + p2[3];
            float mean = t1 * (1.f / 384.f);
            float var  = t2 * (1.f / 384.f) - mean * mean;
            rstd[mt] = rsqrtf(var + 1e-5f);
            rm[mt]   = rstd[mt] * mean;
        }
    }

    float s1[4] = {0.f,0.f,0.f,0.f}, s2[4] = {0.f,0.f,0.f,0.f};
    #pragma unroll
    for (int nt = 0; nt < NT; ++nt) {
        const int f0 = FB + nt * 16 + q * 4;
        f32x4 c4 = *(const f32x4*)&cb[f0];
        f32x4 g4;
        if (LNIN) g4 = *(const f32x4*)&Gf[f0];
        #pragma unroll
        for (int mt = 0; mt < 4; ++mt) {
            f32x4 vv;
            #pragma unroll
            for (int r = 0; r < 4; ++r) {
                float v;
                if (LNIN) v = fmaf(rstd[mt], acc[mt][nt][r], fmaf(-rm[mt], g4[r], c4[r]));
                else      v = acc[mt][nt][r] + c4[r];
                if (SILU_) v = silu(v);
                if (MASK) v *= mk[mt];
                if (STATS) { s1[mt] += v; s2[mt] += v * v; }
                vv[r] = v;
            }
            *(s16x4*)&xs[mt * 16 + ln][f0] = pack4(vv);
        }
    }
    if (STATS) {
        #pragma unroll
        for (int mt = 0; mt < 4; ++mt) {
            s1[mt] += __shfl_xor(s1[mt], 16); s2[mt] += __shfl_xor(s2[mt], 16);
            s1[mt] += __shfl_xor(s1[mt], 32); s2[mt] += __shfl_xor(s2[mt], 32);
        }
        if (q == 0) {
            #pragma unroll
            for (int mt = 0; mt < 4; ++mt) {
                sc1[mt * 16 + ln][w] = s1[mt];
                sc2[mt * 16 + ln][w] = s2[mt];
            }
        }
    }
    BAR();   // writes (xs and sc) visible before next layer
}

__global__ __launch_bounds__(256, 2) void upxi64(
    const float* __restrict__ s_parent, const float* __restrict__ mu_k,
    const float* __restrict__ R_k,      const float* __restrict__ s_k,
    const int*   __restrict__ a_idx,    const float* __restrict__ node_mask,
    const float* __restrict__ pos01,
    const float* __restrict__ pos_b,
    const float* __restrict__ q_b2,     const float* __restrict__ m_b2,
    const float* __restrict__ m_b3,
    const short* __restrict__ wsb,      const float* __restrict__ cst,
    float* __restrict__ out)
{
    __shared__ short xs[MB][LDA];
    __shared__ float sc1[MB][4];
    __shared__ float sc2[MB][4];
    __shared__ float wmask[MB], wpos[MB];
    __shared__ int   widx[MB];

    const int tid  = threadIdx.x;
    const int w    = tid >> 6;
    const int lane = tid & 63;
    const int q    = lane >> 4;
    const int ln   = lane & 15;

    const int g0 = blockIdx.x * MB;
    const int b  = g0 / Nn;
    const int n0 = g0 % Nn;

    // prefetch Q1 first k-chunk immediately (hidden under scalars+sincos+pos)
    bf16x8 bin[6];
    #pragma unroll
    for (int nt = 0; nt < 6; ++nt)
        bin[nt] = *(const bf16x8*)(wsb + Q1_OFF + ((size_t)(w * 6 + nt) * 12) * 512 + ln * 32 + q * 8);

    if (tid < MB) {
        int gi = b * Nn + n0 + tid;
        int idx = a_idx[gi];
        widx[tid]  = min(max(idx, 0), Kk - 1);
        wmask[tid] = node_mask[gi];
        wpos[tid]  = pos01[gi];
    }
    BAR();

    const float* gbase = s_parent + (long)b * Kk * C;

    // ---- pos layer (transposed D): pos_w as A-operand, feats as B-operand ----
    {
        const short* pos_wb = wsb + POS_OFF;
        const bool use_sin = (q < 2);
        const int kb = (q & 1) * 8;
        bf16x8 a[4];
        #pragma unroll
        for (int mt = 0; mt < 4; ++mt) {
            float p = wpos[mt * 16 + ln];
            #pragma unroll
            for (int e = 0; e < 8; ++e) {
                float fr = (float)(1 << (kb + e)) * 3.14159265358979323846f;
                float sv, cv;
                __sincosf(p * fr, &sv, &cv);
                a[mt][e] = f2bf(use_sin ? sv : cv);
            }
        }
        f32x4 acc[4][6];
        #pragma unroll
        for (int mt = 0; mt < 4; ++mt)
            #pragma unroll
            for (int nt = 0; nt < 6; ++nt)
                acc[mt][nt] = (f32x4){0.f, 0.f, 0.f, 0.f};
        #pragma unroll
        for (int nt = 0; nt < 6; ++nt) {
            bf16x8 bfr = *(const bf16x8*)&pos_wb[(w * 6 + nt) * 512 + ln * 32 + q * 8];
            #pragma unroll
            for (int mt = 0; mt < 4; ++mt)
                acc[mt][nt] = __builtin_amdgcn_mfma_f32_16x16x32_bf16(bfr, a[mt], acc[mt][nt], 0, 0, 0);
        }
        float mk[4]; int ix[4];
        #pragma unroll
        for (int mt = 0; mt < 4; ++mt) {
            mk[mt] = wmask[mt * 16 + ln];
            ix[mt] = widx[mt * 16 + ln];
        }
        float s1[4] = {0.f,0.f,0.f,0.f}, s2[4] = {0.f,0.f,0.f,0.f};
        #pragma unroll
        for (int nt = 0; nt < 6; ++nt) {
            const int f0 = w * 96 + nt * 16 + q * 4;
            f32x4 pb4 = *(const f32x4*)&pos_b[f0];
            #pragma unroll
            for (int mt = 0; mt < 4; ++mt) {
                f32x4 g4 = *(const f32x4*)&gbase[(long)ix[mt] * C + f0];
                f32x4 vv;
                #pragma unroll
                for (int r = 0; r < 4; ++r) {
                    float v = (acc[mt][nt][r] + pb4[r]) * mk[mt] + g4[r];
                    s1[mt] += v; s2[mt] += v * v;
                    vv[r] = v;
                }
                *(s16x4*)&xs[mt * 16 + ln][f0] = pack4(vv);
            }
        }
        #pragma unroll
        for (int mt = 0; mt < 4; ++mt) {
            s1[mt] += __shfl_xor(s1[mt], 16); s2[mt] += __shfl_xor(s2[mt], 16);
            s1[mt] += __shfl_xor(s1[mt], 32); s2[mt] += __shfl_xor(s2[mt], 32);
        }
        if (q == 0) {
            #pragma unroll
            for (int mt = 0; mt < 4; ++mt) {
                sc1[mt * 16 + ln][w] = s1[mt];
                sc2[mt * 16 + ln][w] = s2[mt];
            }
        }
    }
    BAR();

    // Q1: LN(q) folded: v = silu(rstd*acc - rm*Gq + Cq)
    layer_ip<384, 6, 6, 384, true,  false, true,  false>(wsb + Q1_OFF, cst + CQ_OFF,
        cst + GQ_OFF, w * 96, wsb + Q2_OFF, w * 96, bin, xs, sc1, sc2, wmask, w, q, ln);
    // Q2: (acc + b2)*mask, stats for m-LN
    layer_ip<384, 6, 4, 384, false, true,  false, true >(wsb + Q2_OFF, q_b2,
        nullptr, w * 96, wsb + M1_OFF, w * 64, bin, xs, sc1, sc2, wmask, w, q, ln);
    // M1: LN(m) folded: v = silu(rstd*acc - rm*Gm + Cm)
    layer_ip<384, 4, 4, 256, true,  false, true,  false>(wsb + M1_OFF, cst + CM_OFF,
        cst + GM_OFF, w * 64, wsb + M2_OFF, w * 64, bin, xs, sc1, sc2, wmask, w, q, ln);
    // M2: silu(acc + b2)
    layer_ip<256, 4, 1, 256, true,  false, false, false>(wsb + M2_OFF, m_b2,
        nullptr, w * 64, wsb + M3_OFF, 0, bin, xs, sc1, sc2, wmask, w, q, ln);

    // ---- tail: 256->3 MFMA transposed (wave w owns m-tile w), tanh*1.5 ----
    {
        const short* W3 = wsb + M3_OFF;
        f32x4 a3 = (f32x4){0.f, 0.f, 0.f, 0.f};
        #pragma unroll
        for (int kc = 0; kc < 8; ++kc) {
            bf16x8 a  = *(const bf16x8*)&xs[w * 16 + ln][kc * 32 + q * 8];
            bf16x8 bf = (kc == 0) ? bin[0]
                      : *(const bf16x8*)(W3 + kc * 512 + ln * 32 + q * 8);
            a3 = __builtin_amdgcn_mfma_f32_16x16x32_bf16(bf, a, a3, 0, 0, 0);
        }
        if (q == 0) {
            int m = w * 16 + ln;
            float mkv = wmask[m];
            #pragma unroll
            for (int r = 0; r < 3; ++r) {
                float v = (a3[r] + m_b3[r]) * mkv;
                sc1[m][r] = tanhf(v) * 1.5f;
            }
        }
    }

    // ---- rigid apply + outputs (same-wave lanes; in-wave order suffices) ----
    if (lane < 16) {
        int m = w * 16 + lane;
        long gi = (long)b * Nn + n0 + m;
        long pk = (long)b * Kk + widx[m];
        float mkv = wmask[m];
        float xv[3], yv[3], xiv[3];
        #pragma unroll
        for (int j = 0; j < 3; ++j) {
            xiv[j] = sc1[m][j];
            float sc = fmaxf(s_k[pk * 3 + j], 1e-8f);
            xv[j] = xiv[j] * sc;
        }
        #pragma unroll
        for (int i = 0; i < 3; ++i) {
            float a = R_k[pk * 9 + i * 3 + 0] * xv[0]
                    + R_k[pk * 9 + i * 3 + 1] * xv[1]
                    + R_k[pk * 9 + i * 3 + 2] * xv[2]
                    + mu_k[pk * 3 + i];
            yv[i] = a * mkv * 10.f;
        }
        float* o0 = out;
        float* o1 = out + (long)Bb * Nn * 3;
        float* o2 = out + (long)Bb * Nn * 6;
        #pragma unroll
        for (int j = 0; j < 3; ++j) { o0[gi * 3 + j] = xiv[j]; o1[gi * 3 + j] = yv[j]; }
        o2[gi] = wpos[m];
    }
}

extern "C" void kernel_launch(void* const* d_in, const int* in_sizes, int n_in,
                              void* d_out, int out_size, void* d_ws, size_t ws_size,
                              hipStream_t stream) {
    const float* s_parent = (const float*)d_in[0];
    const float* mu_k     = (const float*)d_in[1];
    const float* R_k      = (const float*)d_in[2];
    const float* s_k      = (const float*)d_in[3];
    const int*   a_idx    = (const int*)  d_in[4];
    const float* node_mask= (const float*)d_in[5];
    const float* pos01    = (const float*)d_in[6];
    const float* pos_w    = (const float*)d_in[7];
    const float* pos_b    = (const float*)d_in[8];
    const float* q_ln_g   = (const float*)d_in[9];
    const float* q_ln_b   = (const float*)d_in[10];
    const float* q_w1     = (const float*)d_in[11];
    const float* q_b1     = (const float*)d_in[12];
    const float* q_w2     = (const float*)d_in[13];
    const float* q_b2     = (const float*)d_in[14];
    const float* m_ln_g   = (const float*)d_in[15];
    const float* m_ln_b   = (const float*)d_in[16];
    const float* m_w1     = (const float*)d_in[17];
    const float* m_b1     = (const float*)d_in[18];
    const float* m_w2     = (const float*)d_in[19];
    const float* m_b2     = (const float*)d_in[20];
    const float* m_w3     = (const float*)d_in[21];
    const float* m_b3     = (const float*)d_in[22];

    short* wsb = (short*)d_ws;
    float* cst = (float*)(wsb + W_TOTAL);

    prep<<<NCONV + 640, 256, 0, stream>>>(
        pos_w, q_w1, q_w2, m_w1, m_w2, m_w3,
        q_ln_g, q_ln_b, m_ln_g, m_ln_b, q_b1, m_b1, wsb, cst);

    int blocks = (Bb * Nn) / MB;  // 1024
    upxi64<<<blocks, 256, 0, stream>>>(
        s_parent, mu_k, R_k, s_k, a_idx, node_mask, pos01,
        pos_b, q_b2, m_b2, m_b3, wsb, cst, (float*)d_out);
}

// Round 12
// 190.587 us; speedup vs baseline: 1.2389x; 1.0240x over previous
//
#include <hip/hip_runtime.h>
#include <hip/hip_bf16.h>
#include <math.h>

#define C 384
#define NF 16
#define H 256
#define Bb 4
#define Kk 2048
#define Nn 16384
#define MB 64           // nodes per block (4 m-tiles)
#define LDA 392         // act row stride in shorts

typedef __attribute__((ext_vector_type(8))) short bf16x8;
typedef __attribute__((ext_vector_type(4))) float f32x4;
typedef __attribute__((ext_vector_type(4))) short s16x4;

// ws layout (shorts), fragment-linear: [ntile][kchunk][ln(16)][kq(32)]
#define POS_OFF 0            // pos_w  F=384 K=32
#define Q1_OFF  12288        // q_w1*q_ln_g   F=384 K=384
#define Q2_OFF  159744       // q_w2          F=384 K=384
#define M1_OFF  307200       // m_w1*m_ln_g   F=256 K=384
#define M2_OFF  405504       // m_w2          F=256 K=256
#define M3_OFF  471040       // m_w3 padded [16][256]
#define W_TOTAL 475136
#define NCONV   ((W_TOTAL + 255) / 256)
// float constants after the shorts
#define GQ_OFF 0
#define CQ_OFF 384
#define GM_OFF 768
#define CM_OFF 1024

// barrier that does NOT drain vmcnt — weight prefetches stay in flight.
#define BAR() __asm__ volatile("s_waitcnt lgkmcnt(0)\ns_barrier" ::: "memory")

__device__ __attribute__((always_inline)) inline short f2bf(float x) {
    return __builtin_bit_cast(short, __float2bfloat16(x));
}
__device__ __attribute__((always_inline)) inline float bf2f(short s) {
    return __bfloat162float(__builtin_bit_cast(__hip_bfloat16, s));
}
__device__ __attribute__((always_inline)) inline float silu(float v) {
    return v * __builtin_amdgcn_rcpf(1.f + __expf(-v));
}
__device__ __attribute__((always_inline)) inline s16x4 pack4(f32x4 v) {
    __hip_bfloat162 p0 = __float22bfloat162_rn(float2{v[0], v[1]});
    __hip_bfloat162 p1 = __float22bfloat162_rn(float2{v[2], v[3]});
    s16x4 o;
    o[0] = __builtin_bit_cast(short, p0.x);
    o[1] = __builtin_bit_cast(short, p0.y);
    o[2] = __builtin_bit_cast(short, p1.x);
    o[3] = __builtin_bit_cast(short, p1.y);
    return o;
}

// ---- prep: weight f32->bf16 fragment swizzle (blocks < NCONV) + LN-const fold ----
__global__ __launch_bounds__(256) void prep(
    const float* __restrict__ pos_w, const float* __restrict__ q_w1,
    const float* __restrict__ q_w2,  const float* __restrict__ m_w1,
    const float* __restrict__ m_w2,  const float* __restrict__ m_w3,
    const float* __restrict__ q_ln_g, const float* __restrict__ q_ln_b,
    const float* __restrict__ m_ln_g, const float* __restrict__ m_ln_b,
    const float* __restrict__ q_b1,   const float* __restrict__ m_b1,
    short* __restrict__ ws, float* __restrict__ cst)
{
    __shared__ float rg[4], rc[4];
    int tid = threadIdx.x;
    int blk = blockIdx.x;
    if (blk < NCONV) {
        int i = blk * 256 + tid;
        if (i >= W_TOTAL) return;
        const float* src; int off, K;
        if      (i < Q1_OFF) { src = pos_w; off = POS_OFF; K = 32; }
        else if (i < Q2_OFF) { src = q_w1;  off = Q1_OFF;  K = 384; }
        else if (i < M1_OFF) { src = q_w2;  off = Q2_OFF;  K = 384; }
        else if (i < M2_OFF) { src = m_w1;  off = M1_OFF;  K = 384; }
        else if (i < M3_OFF) { src = m_w2;  off = M2_OFF;  K = 256; }
        else                 { src = m_w3;  off = M3_OFF;  K = 256; }
        int t = i - off;
        int chunk = t >> 9, r = t & 511;
        int ln = r >> 5, kq = r & 31;
        int NKm = K >> 5;
        int ntg = chunk / NKm, kk = chunk - ntg * NKm;
        int f = ntg * 16 + ln, k = kk * 32 + kq;
        float v;
        if (off == M3_OFF) v = (f < 3) ? m_w3[f * 256 + k] : 0.f;
        else               v = src[(size_t)f * K + k];
        if (off == Q1_OFF) v *= q_ln_g[k];
        if (off == M1_OFF) v *= m_ln_g[k];
        ws[i] = f2bf(v);
        return;
    }
    int f = blk - NCONV;   // 0..639
    const float *Wsrc, *lng, *lnb, *bias; int fr, go, co;
    if (f < 384) { Wsrc = q_w1; lng = q_ln_g; lnb = q_ln_b; bias = q_b1; fr = f;      go = GQ_OFF; co = CQ_OFF; }
    else         { Wsrc = m_w1; lng = m_ln_g; lnb = m_ln_b; bias = m_b1; fr = f - 384; go = GM_OFF; co = CM_OFF; }
    float g = 0.f, c = 0.f;
    for (int k = tid; k < 384; k += 256) {
        float wv = Wsrc[(size_t)fr * 384 + k];
        g += bf2f(f2bf(wv * lng[k]));   // match MFMA's bf16-rounded weights
        c += wv * lnb[k];
    }
    #pragma unroll
    for (int d = 1; d < 64; d <<= 1) { g += __shfl_xor(g, d); c += __shfl_xor(c, d); }
    if ((tid & 63) == 0) { rg[tid >> 6] = g; rc[tid >> 6] = c; }
    __syncthreads();
    if (tid == 0) {
        cst[go + fr] = rg[0] + rg[1] + rg[2] + rg[3];
        cst[co + fr] = rc[0] + rc[1] + rc[2] + rc[3] + bias[fr];
    }
}

// In-place FC layer: R8-proven kc+=2 double-step (two B buffers — no spill),
// cross-layer bin prefetch rides through BAR(). Transposed D (weights as
// A-operand): thread (q,ln) holds D[f=FB+nt*16+q*4+r][m=mt*16+ln].
template<int K, int NT, int NTN, int KN, bool SILU_, bool MASK, bool LNIN, bool STATS>
__device__ __attribute__((always_inline)) inline void layer_ip(
    const short* __restrict__ W, const float* __restrict__ cb,
    const float* __restrict__ Gf, int FB,
    const short* __restrict__ Wn, int FBn,
    bf16x8 (&bin)[6],
    short (*__restrict__ xs)[LDA],
    float (*__restrict__ sc1)[4], float (*__restrict__ sc2)[4],
    const float* __restrict__ wmask, int w, int q, int ln)
{
    constexpr int NK = K / 32;
    const short* bp[NT];
    #pragma unroll
    for (int nt = 0; nt < NT; ++nt)
        bp[nt] = W + ((size_t)(FB / 16 + nt) * NK) * 512 + ln * 32 + q * 8;

    f32x4 acc[4][NT];
    #pragma unroll
    for (int mt = 0; mt < 4; ++mt)
        #pragma unroll
        for (int nt = 0; nt < NT; ++nt)
            acc[mt][nt] = (f32x4){0.f, 0.f, 0.f, 0.f};

    bf16x8 b0[NT], b1[NT], a0[4], a1[4];
    #pragma unroll
    for (int nt = 0; nt < NT; ++nt) b0[nt] = bin[nt];   // prefetched first chunk
    #pragma unroll
    for (int mt = 0; mt < 4; ++mt) a0[mt] = *(const bf16x8*)&xs[mt * 16 + ln][q * 8];

    #pragma unroll
    for (int kc = 0; kc < NK; kc += 2) {
        #pragma unroll
        for (int nt = 0; nt < NT; ++nt) b1[nt] = *(const bf16x8*)(bp[nt] + (kc + 1) * 512);
        #pragma unroll
        for (int mt = 0; mt < 4; ++mt) a1[mt] = *(const bf16x8*)&xs[mt * 16 + ln][(kc + 1) * 32 + q * 8];
        #pragma unroll
        for (int nt = 0; nt < NT; ++nt)
            #pragma unroll
            for (int mt = 0; mt < 4; ++mt)
                acc[mt][nt] = __builtin_amdgcn_mfma_f32_16x16x32_bf16(b0[nt], a0[mt], acc[mt][nt], 0, 0, 0);
        if (kc + 2 < NK) {
            #pragma unroll
            for (int nt = 0; nt < NT; ++nt) b0[nt] = *(const bf16x8*)(bp[nt] + (kc + 2) * 512);
            #pragma unroll
            for (int mt = 0; mt < 4; ++mt) a0[mt] = *(const bf16x8*)&xs[mt * 16 + ln][(kc + 2) * 32 + q * 8];
        }
        #pragma unroll
        for (int nt = 0; nt < NT; ++nt)
            #pragma unroll
            for (int mt = 0; mt < 4; ++mt)
                acc[mt][nt] = __builtin_amdgcn_mfma_f32_16x16x32_bf16(b1[nt], a1[mt], acc[mt][nt], 0, 0, 0);
    }

    // prefetch NEXT layer's first k-chunk — BAR() keeps it in flight
    #pragma unroll
    for (int nt = 0; nt < NTN; ++nt)
        bin[nt] = *(const bf16x8*)(Wn + ((size_t)(FBn / 16 + nt) * (KN / 32)) * 512 + ln * 32 + q * 8);

    BAR();   // all reads of xs complete before any in-place write (lgkm only)

    float mk[4], rstd[4], rm[4];
    #pragma unroll
    for (int mt = 0; mt < 4; ++mt) {
        int m = mt * 16 + ln;
        if (MASK) mk[mt] = wmask[m];
        if (LNIN) {
            f32x4 p1 = *(const f32x4*)&sc1[m][0];
            f32x4 p2 = *(const f32x4*)&sc2[m][0];
            float t1 = p1[0] + p1[1] + p1[2] + p1[3];
            float t2 = p2[0] + p2[1] + p2[2] + p2[3];
            float mean = t1 * (1.f / 384.f);
            float var  = t2 * (1.f / 384.f) - mean * mean;
            rstd[mt] = rsqrtf(var + 1e-5f);
            rm[mt]   = rstd[mt] * mean;
        }
    }

    float s1[4] = {0.f,0.f,0.f,0.f}, s2[4] = {0.f,0.f,0.f,0.f};
    #pragma unroll
    for (int nt = 0; nt < NT; ++nt) {
        const int f0 = FB + nt * 16 + q * 4;
        f32x4 c4 = *(const f32x4*)&cb[f0];
        f32x4 g4;
        if (LNIN) g4 = *(const f32x4*)&Gf[f0];
        #pragma unroll
        for (int mt = 0; mt < 4; ++mt) {
            f32x4 vv;
            #pragma unroll
            for (int r = 0; r < 4; ++r) {
                float v;
                if (LNIN) v = fmaf(rstd[mt], acc[mt][nt][r], fmaf(-rm[mt], g4[r], c4[r]));
                else      v = acc[mt][nt][r] + c4[r];
                if (SILU_) v = silu(v);
                if (MASK) v *= mk[mt];
                if (STATS) { s1[mt] += v; s2[mt] += v * v; }
                vv[r] = v;
            }
            *(s16x4*)&xs[mt * 16 + ln][f0] = pack4(vv);
        }
    }
    if (STATS) {
        #pragma unroll
        for (int mt = 0; mt < 4; ++mt) {
            s1[mt] += __shfl_xor(s1[mt], 16); s2[mt] += __shfl_xor(s2[mt], 16);
            s1[mt] += __shfl_xor(s1[mt], 32); s2[mt] += __shfl_xor(s2[mt], 32);
        }
        if (q == 0) {
            #pragma unroll
            for (int mt = 0; mt < 4; ++mt) {
                sc1[mt * 16 + ln][w] = s1[mt];
                sc2[mt * 16 + ln][w] = s2[mt];
            }
        }
    }
    BAR();   // writes (xs and sc) visible before next layer
}

__global__ __launch_bounds__(256, 2) void upxi64(
    const float* __restrict__ s_parent, const float* __restrict__ mu_k,
    const float* __restrict__ R_k,      const float* __restrict__ s_k,
    const int*   __restrict__ a_idx,    const float* __restrict__ node_mask,
    const float* __restrict__ pos01,
    const float* __restrict__ pos_b,
    const float* __restrict__ q_b2,     const float* __restrict__ m_b2,
    const float* __restrict__ m_b3,
    const short* __restrict__ wsb,      const float* __restrict__ cst,
    float* __restrict__ out)
{
    __shared__ short xs[MB][LDA];
    __shared__ float sc1[MB][4];
    __shared__ float sc2[MB][4];
    __shared__ float wmask[MB], wpos[MB];
    __shared__ int   widx[MB];

    const int tid  = threadIdx.x;
    const int w    = tid >> 6;
    const int lane = tid & 63;
    const int q    = lane >> 4;
    const int ln   = lane & 15;

    const int g0 = blockIdx.x * MB;
    const int b  = g0 / Nn;
    const int n0 = g0 % Nn;

    // prefetch Q1 first k-chunk immediately (hidden under scalars+sincos+pos)
    bf16x8 bin[6];
    #pragma unroll
    for (int nt = 0; nt < 6; ++nt)
        bin[nt] = *(const bf16x8*)(wsb + Q1_OFF + ((size_t)(w * 6 + nt) * 12) * 512 + ln * 32 + q * 8);

    if (tid < MB) {
        int gi = b * Nn + n0 + tid;
        int idx = a_idx[gi];
        widx[tid]  = min(max(idx, 0), Kk - 1);
        wmask[tid] = node_mask[gi];
        wpos[tid]  = pos01[gi];
    }
    BAR();

    const float* gbase = s_parent + (long)b * Kk * C;

    // ---- pos layer (transposed D): pos_w as A-operand, feats as B-operand ----
    {
        const short* pos_wb = wsb + POS_OFF;
        const bool use_sin = (q < 2);
        const int kb = (q & 1) * 8;
        bf16x8 a[4];
        #pragma unroll
        for (int mt = 0; mt < 4; ++mt) {
            float p = wpos[mt * 16 + ln];
            #pragma unroll
            for (int e = 0; e < 8; ++e) {
                float fr = (float)(1 << (kb + e)) * 3.14159265358979323846f;
                float sv, cv;
                __sincosf(p * fr, &sv, &cv);
                a[mt][e] = f2bf(use_sin ? sv : cv);
            }
        }
        f32x4 acc[4][6];
        #pragma unroll
        for (int mt = 0; mt < 4; ++mt)
            #pragma unroll
            for (int nt = 0; nt < 6; ++nt)
                acc[mt][nt] = (f32x4){0.f, 0.f, 0.f, 0.f};
        #pragma unroll
        for (int nt = 0; nt < 6; ++nt) {
            bf16x8 bfr = *(const bf16x8*)&pos_wb[(w * 6 + nt) * 512 + ln * 32 + q * 8];
            #pragma unroll
            for (int mt = 0; mt < 4; ++mt)
                acc[mt][nt] = __builtin_amdgcn_mfma_f32_16x16x32_bf16(bfr, a[mt], acc[mt][nt], 0, 0, 0);
        }
        float mk[4]; int ix[4];
        #pragma unroll
        for (int mt = 0; mt < 4; ++mt) {
            mk[mt] = wmask[mt * 16 + ln];
            ix[mt] = widx[mt * 16 + ln];
        }
        float s1[4] = {0.f,0.f,0.f,0.f}, s2[4] = {0.f,0.f,0.f,0.f};
        #pragma unroll
        for (int nt = 0; nt < 6; ++nt) {
            const int f0 = w * 96 + nt * 16 + q * 4;
            f32x4 pb4 = *(const f32x4*)&pos_b[f0];
            #pragma unroll
            for (int mt = 0; mt < 4; ++mt) {
                f32x4 g4 = *(const f32x4*)&gbase[(long)ix[mt] * C + f0];
                f32x4 vv;
                #pragma unroll
                for (int r = 0; r < 4; ++r) {
                    float v = (acc[mt][nt][r] + pb4[r]) * mk[mt] + g4[r];
                    s1[mt] += v; s2[mt] += v * v;
                    vv[r] = v;
                }
                *(s16x4*)&xs[mt * 16 + ln][f0] = pack4(vv);
            }
        }
        #pragma unroll
        for (int mt = 0; mt < 4; ++mt) {
            s1[mt] += __shfl_xor(s1[mt], 16); s2[mt] += __shfl_xor(s2[mt], 16);
            s1[mt] += __shfl_xor(s1[mt], 32); s2[mt] += __shfl_xor(s2[mt], 32);
        }
        if (q == 0) {
            #pragma unroll
            for (int mt = 0; mt < 4; ++mt) {
                sc1[mt * 16 + ln][w] = s1[mt];
                sc2[mt * 16 + ln][w] = s2[mt];
            }
        }
    }
    BAR();

    // Q1: LN(q) folded: v = silu(rstd*acc - rm*Gq + Cq)
    layer_ip<384, 6, 6, 384, true,  false, true,  false>(wsb + Q1_OFF, cst + CQ_OFF,
        cst + GQ_OFF, w * 96, wsb + Q2_OFF, w * 96, bin, xs, sc1, sc2, wmask, w, q, ln);
    // Q2: (acc + b2)*mask, stats for m-LN
    layer_ip<384, 6, 4, 384, false, true,  false, true >(wsb + Q2_OFF, q_b2,
        nullptr, w * 96, wsb + M1_OFF, w * 64, bin, xs, sc1, sc2, wmask, w, q, ln);
    // M1: LN(m) folded: v = silu(rstd*acc - rm*Gm + Cm)
    layer_ip<384, 4, 4, 256, true,  false, true,  false>(wsb + M1_OFF, cst + CM_OFF,
        cst + GM_OFF, w * 64, wsb + M2_OFF, w * 64, bin, xs, sc1, sc2, wmask, w, q, ln);
    // M2: silu(acc + b2)
    layer_ip<256, 4, 1, 256, true,  false, false, false>(wsb + M2_OFF, m_b2,
        nullptr, w * 64, wsb + M3_OFF, 0, bin, xs, sc1, sc2, wmask, w, q, ln);

    // ---- tail: 256->3 MFMA transposed (wave w owns m-tile w), tanh*1.5 ----
    {
        const short* W3 = wsb + M3_OFF;
        f32x4 a3 = (f32x4){0.f, 0.f, 0.f, 0.f};
        #pragma unroll
        for (int kc = 0; kc < 8; ++kc) {
            bf16x8 a  = *(const bf16x8*)&xs[w * 16 + ln][kc * 32 + q * 8];
            bf16x8 bf = (kc == 0) ? bin[0]
                      : *(const bf16x8*)(W3 + kc * 512 + ln * 32 + q * 8);
            a3 = __builtin_amdgcn_mfma_f32_16x16x32_bf16(bf, a, a3, 0, 0, 0);
        }
        if (q == 0) {
            int m = w * 16 + ln;
            float mkv = wmask[m];
            #pragma unroll
            for (int r = 0; r < 3; ++r) {
                float v = (a3[r] + m_b3[r]) * mkv;
                sc1[m][r] = tanhf(v) * 1.5f;
            }
        }
    }

    // ---- rigid apply + outputs (same-wave lanes; in-wave order suffices) ----
    if (lane < 16) {
        int m = w * 16 + lane;
        long gi = (long)b * Nn + n0 + m;
        long pk = (long)b * Kk + widx[m];
        float mkv = wmask[m];
        float xv[3], yv[3], xiv[3];
        #pragma unroll
        for (int j = 0; j < 3; ++j) {
            xiv[j] = sc1[m][j];
            float sc = fmaxf(s_k[pk * 3 + j], 1e-8f);
            xv[j] = xiv[j] * sc;
        }
        #pragma unroll
        for (int i = 0; i < 3; ++i) {
            float a = R_k[pk * 9 + i * 3 + 0] * xv[0]
                    + R_k[pk * 9 + i * 3 + 1] * xv[1]
                    + R_k[pk * 9 + i * 3 + 2] * xv[2]
                    + mu_k[pk * 3 + i];
            yv[i] = a * mkv * 10.f;
        }
        float* o0 = out;
        float* o1 = out + (long)Bb * Nn * 3;
        float* o2 = out + (long)Bb * Nn * 6;
        #pragma unroll
        for (int j = 0; j < 3; ++j) { o0[gi * 3 + j] = xiv[j]; o1[gi * 3 + j] = yv[j]; }
        o2[gi] = wpos[m];
    }
}

extern "C" void kernel_launch(void* const* d_in, const int* in_sizes, int n_in,
                              void* d_out, int out_size, void* d_ws, size_t ws_size,
                              hipStream_t stream) {
    const float* s_parent = (const float*)d_in[0];
    const float* mu_k     = (const float*)d_in[1];
    const float* R_k      = (const float*)d_in[2];
    const float* s_k      = (const float*)d_in[3];
    const int*   a_idx    = (const int*)  d_in[4];
    const float* node_mask= (const float*)d_in[5];
    const float* pos01    = (const float*)d_in[6];
    const float* pos_w    = (const float*)d_in[7];
    const float* pos_b    = (const float*)d_in[8];
    const float* q_ln_g   = (const float*)d_in[9];
    const float* q_ln_b   = (const float*)d_in[10];
    const float* q_w1     = (const float*)d_in[11];
    const float* q_b1     = (const float*)d_in[12];
    const float* q_w2     = (const float*)d_in[13];
    const float* q_b2     = (const float*)d_in[14];
    const float* m_ln_g   = (const float*)d_in[15];
    const float* m_ln_b   = (const float*)d_in[16];
    const float* m_w1     = (const float*)d_in[17];
    const float* m_b1     = (const float*)d_in[18];
    const float* m_w2     = (const float*)d_in[19];
    const float* m_b2     = (const float*)d_in[20];
    const float* m_w3     = (const float*)d_in[21];
    const float* m_b3     = (const float*)d_in[22];

    short* wsb = (short*)d_ws;
    float* cst = (float*)(wsb + W_TOTAL);

    prep<<<NCONV + 640, 256, 0, stream>>>(
        pos_w, q_w1, q_w2, m_w1, m_w2, m_w3,
        q_ln_g, q_ln_b, m_ln_g, m_ln_b, q_b1, m_b1, wsb, cst);

    int blocks = (Bb * Nn) / MB;  // 1024
    upxi64<<<blocks, 256, 0, stream>>>(
        s_parent, mu_k, R_k, s_k, a_idx, node_mask, pos01,
        pos_b, q_b2, m_b2, m_b3, wsb, cst, (float*)d_out);
}